// Round 5
// baseline (184.132 us; speedup 1.0000x reference)
//
#include <hip/hip_runtime.h>

// VQ-VAE quantizer, MI355X (gfx950). B=64, C=D=64, H=32, W=32 -> N=65536 tokens, K=1024 codes.
// Round 9: LDS-staged B-feed (the §5 GEMM pattern), R4 structure otherwise untouched.
//   Post-mortem R8: de-lockstep rotation REGRESSED (62.5->106us) -> concentration theory dead;
//   lockstep reuse was helping. Standing model: B-frag feed is the stall -- 16 waves/CU each
//   pull 4KB/chunk through L1/L2 (~58cyc/instr sustained), tokhalf pairs load IDENTICAL bytes,
//   1-deep register prefetch window (~300-600cyc) < contended L2 service time.
//   Fix: double-buffered LDS staging. Per step: 8x global_load_lds dwordx4 (8KB = both khalf
//   chunks, 2 instr/wave) issued right after __syncthreads -> in flight under the full step's
//   ds_read+MFMA (~1.2k cyc); barrier vmcnt(0) drain is then free. LDS image = cbf's linear
//   fragment order (wave-uniform base + lane*16, m104-safe). ds_read_b128 conflict-free.
//   Floors: MFMA 16.6us, ds_read 512MB@85B/cyc/CU=10.3us, global cbf 256MB (once/block)=4us.
//   Rotation/tie-break reverted: ascending chunks + strict-> == R0-exact selection.
//   Fused finalize via done-counter kept (proven R5-R8).
// Outputs (flat): z_q [4194304] f32 NCHW, loss [1], perplexity [1].

typedef __attribute__((ext_vector_type(8))) short short8;   // 8 bf16 (4 VGPRs)
typedef __attribute__((ext_vector_type(4))) float float4v;  // MFMA C/D frag

#define NELEM 4194304
#define NBLK  1024       // vq grid

// ---- workspace layout (bytes) ----
#define WS_CBF   0        // ushort[131072]: packed split-bf16 codebook, B-frag order (256 KB)
#define WS_C2H   262144   // f32 c2h[1024] = -0.5*||c||^2
#define WS_HIST  266240   // i32 hist[1024]
#define WS_LOSS  270336   // f32 loss_part[32]
#define WS_DONE  270464   // i32 done-counter

__device__ __forceinline__ unsigned bf16_rne(float x) {
    unsigned u = __float_as_uint(x);
    return (u + 0x7fffu + ((u >> 16) & 1u)) >> 16;
}

// async global->LDS, 16B per lane (dest = uniform LDS base + lane*16)
__device__ __forceinline__ void gload_lds16(const ushort* g, ushort* l) {
    __builtin_amdgcn_global_load_lds(
        (const __attribute__((address_space(1))) unsigned int*)g,
        (__attribute__((address_space(3))) unsigned int*)l, 16, 0, 0);
}

// grid = 68 blocks x 256. Blocks 0..63: pack chunk bx (thread (fid=wave, lane) -> one
// contiguous 16B fragment) + c2. Blocks 64..67: zero hist; block 64 zeroes loss_part+done.
// Fragment layout: cbf[((chunk*4 + fid)*64 + lane)*8 + j], fid = split*2 + st,
// lane = kq*16 + col, code = chunk*16+col, dims d = st*32 + kq*8 + j.
__global__ __launch_bounds__(256) void prep_kernel(
    const float* __restrict__ cb, ushort* __restrict__ cbf,
    float* __restrict__ c2h, int* __restrict__ hist, float* __restrict__ loss_part,
    int* __restrict__ done) {
    __shared__ float s_c2[2][16];
    int tid  = threadIdx.x;
    int lane = tid & 63, wave = tid >> 6;
    int quad = lane >> 4, col = lane & 15;
    int bx   = blockIdx.x;

    if (bx >= 64) {
        hist[(bx - 64) * 256 + tid] = 0;
        if (bx == 64) {
            if (tid < 32)  loss_part[tid] = 0.f;
            if (tid == 32) *done = 0;
        }
        return;
    }
    int c = bx, fid = wave;
    int st = fid & 1, split = fid >> 1;
    int code  = c * 16 + col;
    int dbase = st * 32 + quad * 8;
    const float* cp = cb + code * 64 + dbase;
    float4v v0 = *(const float4v*)cp;
    float4v v1 = *(const float4v*)(cp + 4);
    float xs[8] = {v0.x, v0.y, v0.z, v0.w, v1.x, v1.y, v1.z, v1.w};
    short8 frag;
    float ssq = 0.f;
#pragma unroll
    for (int j = 0; j < 8; j++) {
        float x = xs[j];
        ssq = fmaf(x, x, ssq);
        unsigned hb = bf16_rne(x);
        if (split == 0) frag[j] = (short)hb;
        else            frag[j] = (short)bf16_rne(x - __uint_as_float(hb << 16));
    }
    *(short8*)(cbf + ((c * 4 + fid) * 64 + lane) * 8) = frag;   // contiguous 16B store
    if (split == 0) {                    // c2 from exact f32, deterministic order
        ssq += __shfl_xor(ssq, 16);      // sum over kq (lane bits 4..5)
        ssq += __shfl_xor(ssq, 32);
        if (quad == 0) s_c2[st][col] = ssq;
    }
    __syncthreads();
    if (tid < 16) c2h[c * 16 + tid] = -0.5f * (s_c2[0][tid] + s_c2[1][tid]);
}

// grid = 1024 blocks x 256 (4 waves = 4 blocks/CU = 16 waves/CU). Block = 64 tokens.
// wave: tokhalf = wave&1 (32 tokens), khalf = wave>>1 (chunks khalf*32 .. +31, ascending).
__global__ __launch_bounds__(256, 4) void vq_kernel(
    const float* __restrict__ z, const float* __restrict__ cb,
    const ushort* __restrict__ cbf, const float* __restrict__ c2h,
    float* __restrict__ out, float* __restrict__ loss_part, int* __restrict__ hist,
    int* __restrict__ done, const int* __restrict__ flg)
{
    __shared__ ushort s_b[2][2][4][64][8]; // [dbuf][khalf][fid][lane][j] B-frags (16 KB)
    __shared__ float s_q[64 * 65];       // gathered code rows, +1 pad (16.6 KB)
    __shared__ float s_ms[2][64];        // K-half merge: score
    __shared__ int   s_mi[2][64];        // K-half merge: index
    __shared__ int   s_idx[64];
    __shared__ float s_red[4];
    __shared__ int   s_last;

    int tid  = threadIdx.x;
    int lane = tid & 63, wave = tid >> 6;
    int quad = lane >> 4, col = lane & 15;
    int bx   = blockIdx.x;

    int tokbase = bx * 64;
    int bb = tokbase >> 10, hwb = tokbase & 1023;
    const float* zb = z + bb * 65536 + hwb;
    int tokhalf = wave & 1, khalf = wave >> 1;

    // staging role: wave w stages fid pair {(w&1)*2, (w&1)*2+1} of khalf (w>>1)
    int kh_s = wave >> 1, fid_s0 = (wave & 1) * 2, fid_s1 = fid_s0 + 1;

    // prologue: stage chunk 0 of my staging khalf into dbuf 0 (overlaps A-frag loads)
    {
        int ch = kh_s * 32;
        gload_lds16(cbf + ((ch * 4 + fid_s0) * 64 + lane) * 8, &s_b[0][kh_s][fid_s0][0][0]);
        gload_lds16(cbf + ((ch * 4 + fid_s1) * 64 + lane) * 8, &s_b[0][kh_s][fid_s1][0][0]);
    }

    // A-fragments: 2 groups x {hi,lo} x 2 K-steps, loaded once (32 VGPRs) -- R4-identical
    short8 ah[2][2], al[2][2];
#pragma unroll
    for (int g = 0; g < 2; g++) {
        int rel = tokhalf * 32 + g * 16 + col;       // token row m = lane&15
#pragma unroll
        for (int st = 0; st < 2; st++) {
            short8 h8, l8;
#pragma unroll
            for (int j = 0; j < 8; j++) {
                int d = st * 32 + quad * 8 + j;      // k = quad*8+j
                float x = zb[d * 1024 + rel];
                unsigned hb = bf16_rne(x);
                h8[j] = (short)hb;
                l8[j] = (short)bf16_rne(x - __uint_as_float(hb << 16));
            }
            ah[g][st] = h8; al[g][st] = l8;
        }
    }

    float best[2][4]; int bidx[2][4];
#pragma unroll
    for (int g = 0; g < 2; g++)
#pragma unroll
        for (int r = 0; r < 4; r++) { best[g][r] = -1e38f; bidx[g][r] = 0; }

    // k-loop: 32 chunks, double-buffered LDS staging. Per step: barrier (drains prev stage),
    // issue next stage (in flight under this step's ds_read+MFMA), consume current buffer.
    int cur = 0;
    for (int cc = 0; cc < 32; cc++) {
        __syncthreads();                              // stage(cc) landed; buf[cur^1] consumed
        if (cc < 31) {                                // stage(cc+1) -> buf[cur^1], async
            int ch = kh_s * 32 + cc + 1;
            gload_lds16(cbf + ((ch * 4 + fid_s0) * 64 + lane) * 8,
                        &s_b[cur ^ 1][kh_s][fid_s0][0][0]);
            gload_lds16(cbf + ((ch * 4 + fid_s1) * 64 + lane) * 8,
                        &s_b[cur ^ 1][kh_s][fid_s1][0][0]);
        }
        int chunk = khalf * 32 + cc;
        float ini = c2h[chunk * 16 + col];
        int  code = chunk * 16 + col;
        short8 bh0 = *(const short8*)&s_b[cur][khalf][0][lane][0];
        short8 bh1 = *(const short8*)&s_b[cur][khalf][1][lane][0];
        short8 bl0 = *(const short8*)&s_b[cur][khalf][2][lane][0];
        short8 bl1 = *(const short8*)&s_b[cur][khalf][3][lane][0];
#pragma unroll
        for (int g = 0; g < 2; g++) {
            float4v a0 = {ini, ini, ini, ini};        // score = dot - c2/2 (argmax)
            float4v a1 = {0.f, 0.f, 0.f, 0.f};
            a0 = __builtin_amdgcn_mfma_f32_16x16x32_bf16(ah[g][0], bh0, a0, 0, 0, 0);
            a1 = __builtin_amdgcn_mfma_f32_16x16x32_bf16(ah[g][1], bh1, a1, 0, 0, 0);
            a0 = __builtin_amdgcn_mfma_f32_16x16x32_bf16(ah[g][0], bl0, a0, 0, 0, 0);
            a1 = __builtin_amdgcn_mfma_f32_16x16x32_bf16(ah[g][1], bl1, a1, 0, 0, 0);
            a0 = __builtin_amdgcn_mfma_f32_16x16x32_bf16(al[g][0], bh0, a0, 0, 0, 0);
            a1 = __builtin_amdgcn_mfma_f32_16x16x32_bf16(al[g][1], bh1, a1, 0, 0, 0);
            a0 = __builtin_amdgcn_mfma_f32_16x16x32_bf16(al[g][0], bl0, a0, 0, 0, 0);
            a1 = __builtin_amdgcn_mfma_f32_16x16x32_bf16(al[g][1], bl1, a1, 0, 0, 0);
#pragma unroll
            for (int r = 0; r < 4; r++) {
                float s = a0[r] + a1[r];
                if (s > best[g][r]) { best[g][r] = s; bidx[g][r] = code; }  // strict >: first-min
            }
        }
        cur ^= 1;
    }

    // quad-reduction (C row = quad*4+r = token-in-group, col = code lane)
#pragma unroll
    for (int g = 0; g < 2; g++) {
#pragma unroll
        for (int r = 0; r < 4; r++) {
            float s = best[g][r]; int ix = bidx[g][r];
#pragma unroll
            for (int m = 1; m <= 8; m <<= 1) {
                float so = __shfl_xor(s, m);
                int   io = __shfl_xor(ix, m);
                if (so > s || (so == s && io < ix)) { s = so; ix = io; }
            }
            if (col == 0) {
                int t = tokhalf * 32 + g * 16 + quad * 4 + r;
                s_ms[khalf][t] = s; s_mi[khalf][t] = ix;
            }
        }
    }
    __syncthreads();

    // merge K-halves (half0 codes < half1 codes: tie -> half0 = first-min)
    if (tid < 64) {
        float s0 = s_ms[0][tid], s1 = s_ms[1][tid];
        int   i0 = s_mi[0][tid], i1 = s_mi[1][tid];
        int   ix = (s1 > s0) ? i1 : i0;
        s_idx[tid] = ix;
        atomicAdd(&hist[ix], 1);                       // one per token
    }
    __syncthreads();

    // gather selected code rows (wave-uniform row, 256B coalesced)
#pragma unroll
    for (int p = 0; p < 16; p++) {
        int i = p * 256 + tid;
        int t = i >> 6, d = i & 63;
        s_q[t * 65 + d] = cb[s_idx[t] * 64 + d];
    }
    __syncthreads();

    // straight-through output + loss (256B contiguous runs per wave)
    float ls = 0.f;
#pragma unroll 4
    for (int p = 0; p < 16; p++) {
        int i = p * 256 + tid;
        int d = i >> 6, t = i & 63;
        int a = d * 1024 + t;
        float zv = zb[a];
        float q  = s_q[t * 65 + d];                    // bank(t*65+d)=t+d: conflict-free
        float df = q - zv;
        out[bb * 65536 + hwb + a] = zv + df;           // z + (z_q - z)
        ls = fmaf(df, df, ls);
    }
#pragma unroll
    for (int off = 32; off; off >>= 1) ls += __shfl_down(ls, off);
    if (lane == 0) s_red[wave] = ls;
    __syncthreads();
    if (tid == 0) {
        float v = (s_red[0] + s_red[1]) + (s_red[2] + s_red[3]);
        atomicAdd(&loss_part[bx & 31], v);
        __threadfence();                               // release all prior hist/loss atomics
        int old = __hip_atomic_fetch_add(done, 1, __ATOMIC_ACQ_REL, __HIP_MEMORY_SCOPE_AGENT);
        s_last = (old == NBLK - 1) ? 1 : 0;
    }
    __syncthreads();

    // last block: finalize (perplexity + loss) -- replaces the 3rd dispatch
    if (s_last) {
        float v = 0.f;
#pragma unroll
        for (int rr = 0; rr < 4; rr++) {
            int k = rr * 256 + tid;
            float e = (float)__hip_atomic_load(&hist[k], __ATOMIC_RELAXED,
                                               __HIP_MEMORY_SCOPE_AGENT) * (1.0f / 65536.0f);
            v += e * logf(e + 1e-10f);
        }
#pragma unroll
        for (int off = 32; off; off >>= 1) v += __shfl_down(v, off);
        if (lane == 0) s_red[wave] = v;
        float lsum = 0.f;
        if (tid < 32) lsum = __hip_atomic_load(&loss_part[tid], __ATOMIC_RELAXED,
                                               __HIP_MEMORY_SCOPE_AGENT);
#pragma unroll
        for (int off = 16; off; off >>= 1) lsum += __shfl_down(lsum, off);
        __syncthreads();
        if (tid == 0) {
            float sE = (s_red[0] + s_red[1]) + (s_red[2] + s_red[3]);
            out[NELEM + 1] = expf(-sE);                // perplexity
            float m = lsum * (1.0f / (float)NELEM);
            out[NELEM] = (*flg) ? (0.25f * m + m) : 0.0f;  // BETA*mean + mean
        }
    }
}

extern "C" void kernel_launch(void* const* d_in, const int* in_sizes, int n_in,
                              void* d_out, int out_size, void* d_ws, size_t ws_size,
                              hipStream_t stream) {
    const float* z   = (const float*)d_in[0];   // (64,64,32,32) f32 NCHW
    const float* cb  = (const float*)d_in[1];   // (1024,64) f32
    const int*   flg = (const int*)d_in[3];     // flg_train

    float* out = (float*)d_out;
    char*  ws  = (char*)d_ws;

    ushort* cbf       = (ushort*)(ws + WS_CBF);
    float*  c2h       = (float*)(ws + WS_C2H);
    int*    hist      = (int*)(ws + WS_HIST);
    float*  loss_part = (float*)(ws + WS_LOSS);
    int*    done      = (int*)(ws + WS_DONE);

    prep_kernel<<<68, 256, 0, stream>>>(cb, cbf, c2h, hist, loss_part, done);
    vq_kernel<<<NBLK, 256, 0, stream>>>(z, cb, cbf, c2h, out, loss_part, hist, done, flg);
}

// Round 6
// 182.104 us; speedup vs baseline: 1.0111x; 1.0111x over previous
//
#include <hip/hip_runtime.h>

// VQ-VAE quantizer, MI355X (gfx950). B=64, C=D=64, H=32, W=32 -> N=65536 tokens, K=1024 codes.
// Round 10: R4's proven structure + ONE isolated lever: 2-deep register prefetch.
//   Post-mortems: R5 (8 w/CU) -89%, R6/R7 (reg-cap spills) invalid, R8 (rotation, lost L1
//   lockstep reuse) -70%, R9 (per-chunk barrier LDS staging; vmcnt(0) drain x32) -98%.
//   R4 remains best: vq 62.5us, MfmaUtil 21, ~58cyc/vmem sustained -> residual per-chunk
//   stall consistent with contended L2 latency (~600-1000cyc) > 1-chunk prefetch window.
//   R10: unroll k-loop x2 with named A/B prefetch sets (static reg indexing, rule #20):
//   in-flight window doubles to 2 chunk-computes. Same visit order (ascending), same MFMA
//   order/ini, strict-> first-min -> bit-identical selection. +~20 VGPR (cap 128, no spill).
//   Fused finalize via done-counter kept (proven R5-R9). If this nulls, the loop is vmem
//   issue-throughput-bound and this structure is at its ceiling.
// Outputs (flat): z_q [4194304] f32 NCHW, loss [1], perplexity [1].

typedef __attribute__((ext_vector_type(8))) short short8;   // 8 bf16 (4 VGPRs)
typedef __attribute__((ext_vector_type(4))) float float4v;  // MFMA C/D frag

#define NELEM 4194304
#define NBLK  1024       // vq grid

// ---- workspace layout (bytes) ----
#define WS_CBF   0        // ushort[131072]: packed split-bf16 codebook, B-frag order (256 KB)
#define WS_C2H   262144   // f32 c2h[1024] = -0.5*||c||^2
#define WS_HIST  266240   // i32 hist[1024]
#define WS_LOSS  270336   // f32 loss_part[32]
#define WS_DONE  270464   // i32 done-counter

__device__ __forceinline__ unsigned bf16_rne(float x) {
    unsigned u = __float_as_uint(x);
    return (u + 0x7fffu + ((u >> 16) & 1u)) >> 16;
}

// grid = 68 blocks x 256. Blocks 0..63: pack chunk bx (thread (fid=wave, lane) -> one
// contiguous 16B fragment) + c2. Blocks 64..67: zero hist; block 64 zeroes loss_part+done.
// Fragment layout: cbf[((chunk*4 + fid)*64 + lane)*8 + j], fid = split*2 + st,
// lane = kq*16 + col, code = chunk*16+col, dims d = st*32 + kq*8 + j.
__global__ __launch_bounds__(256) void prep_kernel(
    const float* __restrict__ cb, ushort* __restrict__ cbf,
    float* __restrict__ c2h, int* __restrict__ hist, float* __restrict__ loss_part,
    int* __restrict__ done) {
    __shared__ float s_c2[2][16];
    int tid  = threadIdx.x;
    int lane = tid & 63, wave = tid >> 6;
    int quad = lane >> 4, col = lane & 15;
    int bx   = blockIdx.x;

    if (bx >= 64) {
        hist[(bx - 64) * 256 + tid] = 0;
        if (bx == 64) {
            if (tid < 32)  loss_part[tid] = 0.f;
            if (tid == 32) *done = 0;
        }
        return;
    }
    int c = bx, fid = wave;
    int st = fid & 1, split = fid >> 1;
    int code  = c * 16 + col;
    int dbase = st * 32 + quad * 8;
    const float* cp = cb + code * 64 + dbase;
    float4v v0 = *(const float4v*)cp;
    float4v v1 = *(const float4v*)(cp + 4);
    float xs[8] = {v0.x, v0.y, v0.z, v0.w, v1.x, v1.y, v1.z, v1.w};
    short8 frag;
    float ssq = 0.f;
#pragma unroll
    for (int j = 0; j < 8; j++) {
        float x = xs[j];
        ssq = fmaf(x, x, ssq);
        unsigned hb = bf16_rne(x);
        if (split == 0) frag[j] = (short)hb;
        else            frag[j] = (short)bf16_rne(x - __uint_as_float(hb << 16));
    }
    *(short8*)(cbf + ((c * 4 + fid) * 64 + lane) * 8) = frag;   // contiguous 16B store
    if (split == 0) {                    // c2 from exact f32, deterministic order
        ssq += __shfl_xor(ssq, 16);      // sum over kq (lane bits 4..5)
        ssq += __shfl_xor(ssq, 32);
        if (quad == 0) s_c2[st][col] = ssq;
    }
    __syncthreads();
    if (tid < 16) c2h[c * 16 + tid] = -0.5f * (s_c2[0][tid] + s_c2[1][tid]);
}

// one chunk's 8-MFMA + selection (score arithmetic identical to R0/R4)
#define COMPUTE_CHUNK(B0, B1, B2, B3, INI, CODE)                                      \
    do {                                                                              \
        _Pragma("unroll")                                                             \
        for (int g = 0; g < 2; g++) {                                                 \
            float4v a0 = {(INI), (INI), (INI), (INI)};                                \
            float4v a1 = {0.f, 0.f, 0.f, 0.f};                                        \
            a0 = __builtin_amdgcn_mfma_f32_16x16x32_bf16(ah[g][0], B0, a0, 0, 0, 0);  \
            a1 = __builtin_amdgcn_mfma_f32_16x16x32_bf16(ah[g][1], B1, a1, 0, 0, 0);  \
            a0 = __builtin_amdgcn_mfma_f32_16x16x32_bf16(ah[g][0], B2, a0, 0, 0, 0);  \
            a1 = __builtin_amdgcn_mfma_f32_16x16x32_bf16(ah[g][1], B3, a1, 0, 0, 0);  \
            a0 = __builtin_amdgcn_mfma_f32_16x16x32_bf16(al[g][0], B0, a0, 0, 0, 0);  \
            a1 = __builtin_amdgcn_mfma_f32_16x16x32_bf16(al[g][1], B1, a1, 0, 0, 0);  \
            a0 = __builtin_amdgcn_mfma_f32_16x16x32_bf16(al[g][0], B2, a0, 0, 0, 0);  \
            a1 = __builtin_amdgcn_mfma_f32_16x16x32_bf16(al[g][1], B3, a1, 0, 0, 0);  \
            _Pragma("unroll")                                                         \
            for (int r = 0; r < 4; r++) {                                             \
                float s = a0[r] + a1[r];                                              \
                if (s > best[g][r]) { best[g][r] = s; bidx[g][r] = (CODE); }          \
            }                                                                         \
        }                                                                             \
    } while (0)

// NOTE on product order: R0/R4 order was (ah*bh0, ah*bh1, ah*bl0, ah*bl1, al*bh0, ...).
// Here B0..B3 map to (bh0, bh1, bl0, bl1) and the sequence above preserves EXACTLY that
// accumulation order into a0/a1 -> bit-identical scores.

// grid = 1024 blocks x 256 (4 waves = 4 blocks/CU = 16 waves/CU). Block = 64 tokens.
// wave: tokhalf = wave&1 (32 tokens), khalf = wave>>1 (chunks khalf*32 .. +31, ascending).
__global__ __launch_bounds__(256, 4) void vq_kernel(
    const float* __restrict__ z, const float* __restrict__ cb,
    const ushort* __restrict__ cbf, const float* __restrict__ c2h,
    float* __restrict__ out, float* __restrict__ loss_part, int* __restrict__ hist,
    int* __restrict__ done, const int* __restrict__ flg)
{
    __shared__ float s_q[64 * 65];       // gathered code rows, +1 pad (16.6 KB)
    __shared__ float s_ms[2][64];        // K-half merge: score
    __shared__ int   s_mi[2][64];        // K-half merge: index
    __shared__ int   s_idx[64];
    __shared__ float s_red[4];
    __shared__ int   s_last;

    int tid  = threadIdx.x;
    int lane = tid & 63, wave = tid >> 6;
    int quad = lane >> 4, col = lane & 15;
    int bx   = blockIdx.x;

    int tokbase = bx * 64;
    int bb = tokbase >> 10, hwb = tokbase & 1023;
    const float* zb = z + bb * 65536 + hwb;
    int tokhalf = wave & 1, khalf = wave >> 1;

    // A-fragments: 2 groups x {hi,lo} x 2 K-steps, loaded once (32 VGPRs) -- R4-identical
    short8 ah[2][2], al[2][2];
#pragma unroll
    for (int g = 0; g < 2; g++) {
        int rel = tokhalf * 32 + g * 16 + col;       // token row m = lane&15
#pragma unroll
        for (int st = 0; st < 2; st++) {
            short8 h8, l8;
#pragma unroll
            for (int j = 0; j < 8; j++) {
                int d = st * 32 + quad * 8 + j;      // k = quad*8+j
                float x = zb[d * 1024 + rel];
                unsigned hb = bf16_rne(x);
                h8[j] = (short)hb;
                l8[j] = (short)bf16_rne(x - __uint_as_float(hb << 16));
            }
            ah[g][st] = h8; al[g][st] = l8;
        }
    }

    float best[2][4]; int bidx[2][4];
#pragma unroll
    for (int g = 0; g < 2; g++)
#pragma unroll
        for (int r = 0; r < 4; r++) { best[g][r] = -1e38f; bidx[g][r] = 0; }

    // k-loop: 32 chunks, 2-DEEP register prefetch (named sets A/B, x2 unroll), no barriers.
    // Window: loads for chunk cc+2 are in flight across the compute of cc AND cc+1.
    int cbase = khalf * 32;
    const ushort* cw = cbf + lane * 8;
    {
        const ushort* p0 = cw + cbase * 2048;              // chunk cbase+0 -> set A
        short8 nA0 = *(const short8*)(p0 + 0);
        short8 nA1 = *(const short8*)(p0 + 512);
        short8 nA2 = *(const short8*)(p0 + 1024);
        short8 nA3 = *(const short8*)(p0 + 1536);
        float  niA = c2h[cbase * 16 + col];
        const ushort* p1 = cw + (cbase + 1) * 2048;        // chunk cbase+1 -> set B
        short8 nB0 = *(const short8*)(p1 + 0);
        short8 nB1 = *(const short8*)(p1 + 512);
        short8 nB2 = *(const short8*)(p1 + 1024);
        short8 nB3 = *(const short8*)(p1 + 1536);
        float  niB = c2h[(cbase + 1) * 16 + col];

        for (int cc = 0; cc < 32; cc += 2) {
            // even chunk: consume set A, refill A with chunk cc+2
            {
                short8 b0 = nA0, b1 = nA1, b2 = nA2, b3 = nA3;
                float  ini = niA;
                if (cc + 2 < 32) {
                    const ushort* np = cw + (cbase + cc + 2) * 2048;
                    nA0 = *(const short8*)(np + 0);
                    nA1 = *(const short8*)(np + 512);
                    nA2 = *(const short8*)(np + 1024);
                    nA3 = *(const short8*)(np + 1536);
                    niA = c2h[(cbase + cc + 2) * 16 + col];
                }
                int code = (cbase + cc) * 16 + col;
                COMPUTE_CHUNK(b0, b1, b2, b3, ini, code);
            }
            // odd chunk: consume set B, refill B with chunk cc+3
            {
                short8 b0 = nB0, b1 = nB1, b2 = nB2, b3 = nB3;
                float  ini = niB;
                if (cc + 3 < 32) {
                    const ushort* np = cw + (cbase + cc + 3) * 2048;
                    nB0 = *(const short8*)(np + 0);
                    nB1 = *(const short8*)(np + 512);
                    nB2 = *(const short8*)(np + 1024);
                    nB3 = *(const short8*)(np + 1536);
                    niB = c2h[(cbase + cc + 3) * 16 + col];
                }
                int code = (cbase + cc + 1) * 16 + col;
                COMPUTE_CHUNK(b0, b1, b2, b3, ini, code);
            }
        }
    }

    // quad-reduction (C row = quad*4+r = token-in-group, col = code lane)
#pragma unroll
    for (int g = 0; g < 2; g++) {
#pragma unroll
        for (int r = 0; r < 4; r++) {
            float s = best[g][r]; int ix = bidx[g][r];
#pragma unroll
            for (int m = 1; m <= 8; m <<= 1) {
                float so = __shfl_xor(s, m);
                int   io = __shfl_xor(ix, m);
                if (so > s || (so == s && io < ix)) { s = so; ix = io; }
            }
            if (col == 0) {
                int t = tokhalf * 32 + g * 16 + quad * 4 + r;
                s_ms[khalf][t] = s; s_mi[khalf][t] = ix;
            }
        }
    }
    __syncthreads();

    // merge K-halves (half0 codes < half1 codes: tie -> half0 = first-min)
    if (tid < 64) {
        float s0 = s_ms[0][tid], s1 = s_ms[1][tid];
        int   i0 = s_mi[0][tid], i1 = s_mi[1][tid];
        int   ix = (s1 > s0) ? i1 : i0;
        s_idx[tid] = ix;
        atomicAdd(&hist[ix], 1);                       // one per token
    }
    __syncthreads();

    // gather selected code rows (wave-uniform row, 256B coalesced)
#pragma unroll
    for (int p = 0; p < 16; p++) {
        int i = p * 256 + tid;
        int t = i >> 6, d = i & 63;
        s_q[t * 65 + d] = cb[s_idx[t] * 64 + d];
    }
    __syncthreads();

    // straight-through output + loss (256B contiguous runs per wave)
    float ls = 0.f;
#pragma unroll 4
    for (int p = 0; p < 16; p++) {
        int i = p * 256 + tid;
        int d = i >> 6, t = i & 63;
        int a = d * 1024 + t;
        float zv = zb[a];
        float q  = s_q[t * 65 + d];                    // bank(t*65+d)=t+d: conflict-free
        float df = q - zv;
        out[bb * 65536 + hwb + a] = zv + df;           // z + (z_q - z)
        ls = fmaf(df, df, ls);
    }
#pragma unroll
    for (int off = 32; off; off >>= 1) ls += __shfl_down(ls, off);
    if (lane == 0) s_red[wave] = ls;
    __syncthreads();
    if (tid == 0) {
        float v = (s_red[0] + s_red[1]) + (s_red[2] + s_red[3]);
        atomicAdd(&loss_part[bx & 31], v);
        __threadfence();                               // release all prior hist/loss atomics
        int old = __hip_atomic_fetch_add(done, 1, __ATOMIC_ACQ_REL, __HIP_MEMORY_SCOPE_AGENT);
        s_last = (old == NBLK - 1) ? 1 : 0;
    }
    __syncthreads();

    // last block: finalize (perplexity + loss) -- replaces the 3rd dispatch
    if (s_last) {
        float v = 0.f;
#pragma unroll
        for (int rr = 0; rr < 4; rr++) {
            int k = rr * 256 + tid;
            float e = (float)__hip_atomic_load(&hist[k], __ATOMIC_RELAXED,
                                               __HIP_MEMORY_SCOPE_AGENT) * (1.0f / 65536.0f);
            v += e * logf(e + 1e-10f);
        }
#pragma unroll
        for (int off = 32; off; off >>= 1) v += __shfl_down(v, off);
        if (lane == 0) s_red[wave] = v;
        float lsum = 0.f;
        if (tid < 32) lsum = __hip_atomic_load(&loss_part[tid], __ATOMIC_RELAXED,
                                               __HIP_MEMORY_SCOPE_AGENT);
#pragma unroll
        for (int off = 16; off; off >>= 1) lsum += __shfl_down(lsum, off);
        __syncthreads();
        if (tid == 0) {
            float sE = (s_red[0] + s_red[1]) + (s_red[2] + s_red[3]);
            out[NELEM + 1] = expf(-sE);                // perplexity
            float m = lsum * (1.0f / (float)NELEM);
            out[NELEM] = (*flg) ? (0.25f * m + m) : 0.0f;  // BETA*mean + mean
        }
    }
}

extern "C" void kernel_launch(void* const* d_in, const int* in_sizes, int n_in,
                              void* d_out, int out_size, void* d_ws, size_t ws_size,
                              hipStream_t stream) {
    const float* z   = (const float*)d_in[0];   // (64,64,32,32) f32 NCHW
    const float* cb  = (const float*)d_in[1];   // (1024,64) f32
    const int*   flg = (const int*)d_in[3];     // flg_train

    float* out = (float*)d_out;
    char*  ws  = (char*)d_ws;

    ushort* cbf       = (ushort*)(ws + WS_CBF);
    float*  c2h       = (float*)(ws + WS_C2H);
    int*    hist      = (int*)(ws + WS_HIST);
    float*  loss_part = (float*)(ws + WS_LOSS);
    int*    done      = (int*)(ws + WS_DONE);

    prep_kernel<<<68, 256, 0, stream>>>(cb, cbf, c2h, hist, loss_part, done);
    vq_kernel<<<NBLK, 256, 0, stream>>>(z, cb, cbf, c2h, out, loss_part, hist, done, flg);
}

// Round 7
// 167.647 us; speedup vs baseline: 1.0983x; 1.0862x over previous
//
#include <hip/hip_runtime.h>

// VQ-VAE quantizer, MI355X (gfx950). B=64, C=D=64, H=32, W=32 -> N=65536 tokens, K=1024 codes.
// Round 11: re-anchor. k-loop is R4-EXACT (every variant regressed: R5 occupancy, R6/R7 reg
//   caps, R8 rotation broke L1 lockstep reuse, R9 per-chunk barriers, R10 2-deep prefetch
//   defeated compiler vmcnt). Kept: fused finalize (proven R5-R10). Added the one safe lever
//   never isolated: z-path cleanup via LDS (R6-proven pattern, minus R6's reg-cap mistake):
//   - stage 64x64 z tile once, coalesced float4 (kills 2x redundant strided A-frag loads)
//   - A-frags built from LDS (contiguous -> ds_read_b128, 2-way banks = free)
//   - epilogue reads z from LDS instead of re-reading global
//   LDS 34.6 KB < 40 KB (4 blocks/CU keeps 16 waves/CU); VGPR ~56 << 128 cap (no spill).
//   Score arithmetic bit-identical to R0/R4 -> absmax must stay 2.394531.
// Outputs (flat): z_q [4194304] f32 NCHW, loss [1], perplexity [1].

typedef __attribute__((ext_vector_type(8))) short short8;   // 8 bf16 (4 VGPRs)
typedef __attribute__((ext_vector_type(4))) float float4v;  // MFMA C/D frag

#define NELEM 4194304
#define NBLK  1024       // vq grid

// ---- workspace layout (bytes) ----
#define WS_CBF   0        // ushort[131072]: packed split-bf16 codebook, B-frag order (256 KB)
#define WS_C2H   262144   // f32 c2h[1024] = -0.5*||c||^2
#define WS_HIST  266240   // i32 hist[1024]
#define WS_LOSS  270336   // f32 loss_part[32]
#define WS_DONE  270464   // i32 done-counter

__device__ __forceinline__ unsigned bf16_rne(float x) {
    unsigned u = __float_as_uint(x);
    return (u + 0x7fffu + ((u >> 16) & 1u)) >> 16;
}

// grid = 68 blocks x 256. Blocks 0..63: pack chunk bx (thread (fid=wave, lane) -> one
// contiguous 16B fragment) + c2. Blocks 64..67: zero hist; block 64 zeroes loss_part+done.
// Fragment layout: cbf[((chunk*4 + fid)*64 + lane)*8 + j], fid = split*2 + st,
// lane = kq*16 + col, code = chunk*16+col, dims d = st*32 + kq*8 + j.
__global__ __launch_bounds__(256) void prep_kernel(
    const float* __restrict__ cb, ushort* __restrict__ cbf,
    float* __restrict__ c2h, int* __restrict__ hist, float* __restrict__ loss_part,
    int* __restrict__ done) {
    __shared__ float s_c2[2][16];
    int tid  = threadIdx.x;
    int lane = tid & 63, wave = tid >> 6;
    int quad = lane >> 4, col = lane & 15;
    int bx   = blockIdx.x;

    if (bx >= 64) {
        hist[(bx - 64) * 256 + tid] = 0;
        if (bx == 64) {
            if (tid < 32)  loss_part[tid] = 0.f;
            if (tid == 32) *done = 0;
        }
        return;
    }
    int c = bx, fid = wave;
    int st = fid & 1, split = fid >> 1;
    int code  = c * 16 + col;
    int dbase = st * 32 + quad * 8;
    const float* cp = cb + code * 64 + dbase;
    float4v v0 = *(const float4v*)cp;
    float4v v1 = *(const float4v*)(cp + 4);
    float xs[8] = {v0.x, v0.y, v0.z, v0.w, v1.x, v1.y, v1.z, v1.w};
    short8 frag;
    float ssq = 0.f;
#pragma unroll
    for (int j = 0; j < 8; j++) {
        float x = xs[j];
        ssq = fmaf(x, x, ssq);
        unsigned hb = bf16_rne(x);
        if (split == 0) frag[j] = (short)hb;
        else            frag[j] = (short)bf16_rne(x - __uint_as_float(hb << 16));
    }
    *(short8*)(cbf + ((c * 4 + fid) * 64 + lane) * 8) = frag;   // contiguous 16B store
    if (split == 0) {                    // c2 from exact f32, deterministic order
        ssq += __shfl_xor(ssq, 16);      // sum over kq (lane bits 4..5)
        ssq += __shfl_xor(ssq, 32);
        if (quad == 0) s_c2[st][col] = ssq;
    }
    __syncthreads();
    if (tid < 16) c2h[c * 16 + tid] = -0.5f * (s_c2[0][tid] + s_c2[1][tid]);
}

// grid = 1024 blocks x 256 (4 waves = 4 blocks/CU = 16 waves/CU). Block = 64 tokens.
// wave: tokhalf = wave&1 (32 tokens), khalf = wave>>1 (chunks khalf*32 .. +31, ascending).
__global__ __launch_bounds__(256, 4) void vq_kernel(
    const float* __restrict__ z, const float* __restrict__ cb,
    const ushort* __restrict__ cbf, const float* __restrict__ c2h,
    float* __restrict__ out, float* __restrict__ loss_part, int* __restrict__ hist,
    int* __restrict__ done, const int* __restrict__ flg)
{
    __shared__ float s_z[64 * 65];       // staged z tile [tok][d], +1 pad (16.6 KB)
    __shared__ float s_q[64 * 65];       // gathered code rows  [tok][d] (16.6 KB)
    __shared__ float s_ms[2][64];        // K-half merge: score
    __shared__ int   s_mi[2][64];        // K-half merge: index
    __shared__ int   s_idx[64];
    __shared__ float s_red[4];
    __shared__ int   s_last;

    int tid  = threadIdx.x;
    int lane = tid & 63, wave = tid >> 6;
    int quad = lane >> 4, col = lane & 15;
    int bx   = blockIdx.x;

    int tokbase = bx * 64;
    int bb = tokbase >> 10, hwb = tokbase & 1023;
    const float* zb = z + bb * 65536 + hwb;
    int tokhalf = wave & 1, khalf = wave >> 1;

    // ---- stage z tile to LDS, coalesced float4 (z read ONCE per block; R6-proven) ----
#pragma unroll
    for (int it = 0; it < 4; it++) {
        int idx = it * 256 + tid;         // 0..1023
        int d = idx >> 4, t4 = (idx & 15) * 4;
        float4v v = *(const float4v*)(zb + d * 1024 + t4);
        s_z[(t4 + 0) * 65 + d] = v.x;
        s_z[(t4 + 1) * 65 + d] = v.y;
        s_z[(t4 + 2) * 65 + d] = v.z;
        s_z[(t4 + 3) * 65 + d] = v.w;
    }
    __syncthreads();

    // A-fragments from LDS: 2 groups x {hi,lo} x 2 K-steps (32 VGPRs) -- values == R4
    short8 ah[2][2], al[2][2];
#pragma unroll
    for (int g = 0; g < 2; g++) {
        int rel = tokhalf * 32 + g * 16 + col;       // token row m = lane&15
        const float* zr = &s_z[rel * 65];
#pragma unroll
        for (int st = 0; st < 2; st++) {
            short8 h8, l8;
#pragma unroll
            for (int j = 0; j < 8; j++) {
                float x = zr[st * 32 + quad * 8 + j];   // contiguous -> ds_read_b128
                unsigned hb = bf16_rne(x);
                h8[j] = (short)hb;
                l8[j] = (short)bf16_rne(x - __uint_as_float(hb << 16));
            }
            ah[g][st] = h8; al[g][st] = l8;
        }
    }

    float best[2][4]; int bidx[2][4];
#pragma unroll
    for (int g = 0; g < 2; g++)
#pragma unroll
        for (int r = 0; r < 4; r++) { best[g][r] = -1e38f; bidx[g][r] = 0; }

    // ---- k-loop: R4-EXACT. 32 chunks, 1-deep register prefetch, ascending, no barriers ----
    int cbase = khalf * 32;
    const ushort* cw = cbf + lane * 8;
    {
        const ushort* p0 = cw + cbase * 2048;
        short8 nb0 = *(const short8*)(p0 + 0);
        short8 nb1 = *(const short8*)(p0 + 512);
        short8 nb2 = *(const short8*)(p0 + 1024);
        short8 nb3 = *(const short8*)(p0 + 1536);
        float  nini = c2h[cbase * 16 + col];
        for (int cc = 0; cc < 32; cc++) {
            short8 bh0 = nb0, bh1 = nb1, bl0 = nb2, bl1 = nb3;
            float  ini = nini;
            if (cc < 31) {                            // prefetch next chunk
                const ushort* np = cw + (cbase + cc + 1) * 2048;
                nb0 = *(const short8*)(np + 0);
                nb1 = *(const short8*)(np + 512);
                nb2 = *(const short8*)(np + 1024);
                nb3 = *(const short8*)(np + 1536);
                nini = c2h[(cbase + cc + 1) * 16 + col];
            }
            int code = (cbase + cc) * 16 + col;
#pragma unroll
            for (int g = 0; g < 2; g++) {
                float4v a0 = {ini, ini, ini, ini};    // score = dot - c2/2 (argmax)
                float4v a1 = {0.f, 0.f, 0.f, 0.f};
                a0 = __builtin_amdgcn_mfma_f32_16x16x32_bf16(ah[g][0], bh0, a0, 0, 0, 0);
                a1 = __builtin_amdgcn_mfma_f32_16x16x32_bf16(ah[g][1], bh1, a1, 0, 0, 0);
                a0 = __builtin_amdgcn_mfma_f32_16x16x32_bf16(ah[g][0], bl0, a0, 0, 0, 0);
                a1 = __builtin_amdgcn_mfma_f32_16x16x32_bf16(ah[g][1], bl1, a1, 0, 0, 0);
                a0 = __builtin_amdgcn_mfma_f32_16x16x32_bf16(al[g][0], bh0, a0, 0, 0, 0);
                a1 = __builtin_amdgcn_mfma_f32_16x16x32_bf16(al[g][1], bh1, a1, 0, 0, 0);
                a0 = __builtin_amdgcn_mfma_f32_16x16x32_bf16(al[g][0], bl0, a0, 0, 0, 0);
                a1 = __builtin_amdgcn_mfma_f32_16x16x32_bf16(al[g][1], bl1, a1, 0, 0, 0);
#pragma unroll
                for (int r = 0; r < 4; r++) {
                    float s = a0[r] + a1[r];
                    if (s > best[g][r]) { best[g][r] = s; bidx[g][r] = code; }  // strict >: first-min
                }
            }
        }
    }

    // quad-reduction (C row = quad*4+r = token-in-group, col = code lane)
#pragma unroll
    for (int g = 0; g < 2; g++) {
#pragma unroll
        for (int r = 0; r < 4; r++) {
            float s = best[g][r]; int ix = bidx[g][r];
#pragma unroll
            for (int m = 1; m <= 8; m <<= 1) {
                float so = __shfl_xor(s, m);
                int   io = __shfl_xor(ix, m);
                if (so > s || (so == s && io < ix)) { s = so; ix = io; }
            }
            if (col == 0) {
                int t = tokhalf * 32 + g * 16 + quad * 4 + r;
                s_ms[khalf][t] = s; s_mi[khalf][t] = ix;
            }
        }
    }
    __syncthreads();

    // merge K-halves (half0 codes < half1 codes: tie -> half0 = first-min)
    if (tid < 64) {
        float s0 = s_ms[0][tid], s1 = s_ms[1][tid];
        int   i0 = s_mi[0][tid], i1 = s_mi[1][tid];
        int   ix = (s1 > s0) ? i1 : i0;
        s_idx[tid] = ix;
        atomicAdd(&hist[ix], 1);                       // one per token
    }
    __syncthreads();

    // gather selected code rows (wave-uniform row, 256B coalesced)
#pragma unroll
    for (int p = 0; p < 16; p++) {
        int i = p * 256 + tid;
        int t = i >> 6, d = i & 63;
        s_q[t * 65 + d] = cb[s_idx[t] * 64 + d];
    }
    __syncthreads();

    // straight-through output + loss; z from LDS (no global re-read)
    float ls = 0.f;
#pragma unroll 4
    for (int p = 0; p < 16; p++) {
        int i = p * 256 + tid;
        int d = i >> 6, t = i & 63;
        int a = d * 1024 + t;
        float zv = s_z[t * 65 + d];                    // bank = t+d: conflict-free
        float q  = s_q[t * 65 + d];
        float df = q - zv;
        out[bb * 65536 + hwb + a] = zv + df;           // z + (z_q - z)
        ls = fmaf(df, df, ls);
    }
#pragma unroll
    for (int off = 32; off; off >>= 1) ls += __shfl_down(ls, off);
    if (lane == 0) s_red[wave] = ls;
    __syncthreads();
    if (tid == 0) {
        float v = (s_red[0] + s_red[1]) + (s_red[2] + s_red[3]);
        atomicAdd(&loss_part[bx & 31], v);
        __threadfence();                               // release all prior hist/loss atomics
        int old = __hip_atomic_fetch_add(done, 1, __ATOMIC_ACQ_REL, __HIP_MEMORY_SCOPE_AGENT);
        s_last = (old == NBLK - 1) ? 1 : 0;
    }
    __syncthreads();

    // last block: finalize (perplexity + loss) -- replaces the 3rd dispatch
    if (s_last) {
        float v = 0.f;
#pragma unroll
        for (int rr = 0; rr < 4; rr++) {
            int k = rr * 256 + tid;
            float e = (float)__hip_atomic_load(&hist[k], __ATOMIC_RELAXED,
                                               __HIP_MEMORY_SCOPE_AGENT) * (1.0f / 65536.0f);
            v += e * logf(e + 1e-10f);
        }
#pragma unroll
        for (int off = 32; off; off >>= 1) v += __shfl_down(v, off);
        if (lane == 0) s_red[wave] = v;
        float lsum = 0.f;
        if (tid < 32) lsum = __hip_atomic_load(&loss_part[tid], __ATOMIC_RELAXED,
                                               __HIP_MEMORY_SCOPE_AGENT);
#pragma unroll
        for (int off = 16; off; off >>= 1) lsum += __shfl_down(lsum, off);
        __syncthreads();
        if (tid == 0) {
            float sE = (s_red[0] + s_red[1]) + (s_red[2] + s_red[3]);
            out[NELEM + 1] = expf(-sE);                // perplexity
            float m = lsum * (1.0f / (float)NELEM);
            out[NELEM] = (*flg) ? (0.25f * m + m) : 0.0f;  // BETA*mean + mean
        }
    }
}

extern "C" void kernel_launch(void* const* d_in, const int* in_sizes, int n_in,
                              void* d_out, int out_size, void* d_ws, size_t ws_size,
                              hipStream_t stream) {
    const float* z   = (const float*)d_in[0];   // (64,64,32,32) f32 NCHW
    const float* cb  = (const float*)d_in[1];   // (1024,64) f32
    const int*   flg = (const int*)d_in[3];     // flg_train

    float* out = (float*)d_out;
    char*  ws  = (char*)d_ws;

    ushort* cbf       = (ushort*)(ws + WS_CBF);
    float*  c2h       = (float*)(ws + WS_C2H);
    int*    hist      = (int*)(ws + WS_HIST);
    float*  loss_part = (float*)(ws + WS_LOSS);
    int*    done      = (int*)(ws + WS_DONE);

    prep_kernel<<<68, 256, 0, stream>>>(cb, cbf, c2h, hist, loss_part, done);
    vq_kernel<<<NBLK, 256, 0, stream>>>(z, cb, cbf, c2h, out, loss_part, hist, done, flg);
}

// Round 8
// 127.453 us; speedup vs baseline: 1.4447x; 1.3154x over previous
//
#include <hip/hip_runtime.h>

// VQ-VAE quantizer, MI355X (gfx950). B=64, C=D=64, H=32, W=32 -> N=65536 tokens, K=1024 codes.
// Round 12: REVERT to R0-exact 3-dispatch structure + s_setprio freeroll.
//   Session-wide confound found: every round R5-R11 carried a fused finalize whose
//   __threadfence + ACQ_REL done-atomic emit per-block buffer_wbl2/inv cache maintenance.
//   1024 such events overlap in-flight k-loops -> ~45us penalty at 1024 blocks (~22us at
//   512). Corrected: rotation/s_z were ~neutral, 2-deep/LDS-B truly negative; NO lever ever
//   beat R0's k-loop. Fusion also never paid e2e (non-vq time ~58-60us in every round).
//   R12 = R0 byte-for-byte (3 dispatches, stream ordering = free visibility) plus ONE
//   zero-numerics-risk tweak: s_setprio(1) around each chunk's MFMA cluster. The k-loop's
//   16 waves/CU are barrier-free and drift independently -- the regime where setprio
//   measured +4-7% (m191), unlike barrier-locked GEMM (m190 null).
//   absmax must stay exactly 2.394531.
// Outputs (flat): z_q [4194304] f32 NCHW, loss [1], perplexity [1].

typedef __attribute__((ext_vector_type(8))) short short8;   // 8 bf16 (4 VGPRs)
typedef __attribute__((ext_vector_type(4))) float float4v;  // MFMA C/D frag

#define NELEM 4194304

// ---- workspace layout (bytes) ----
#define WS_CBF   0        // ushort[131072]: packed split-bf16 codebook, B-frag order (256 KB)
#define WS_C2H   262144   // f32 c2h[1024] = -0.5*||c||^2
#define WS_HIST  266240   // i32 hist[1024]
#define WS_LOSS  270336   // f32 loss_part[64]

__device__ __forceinline__ unsigned bf16_rne(float x) {
    unsigned u = __float_as_uint(x);
    return (u + 0x7fffu + ((u >> 16) & 1u)) >> 16;
}

// grid = 68 blocks x 256. Blocks 0..63: pack chunk bx (thread (fid=wave, lane) -> one
// contiguous 16B fragment) + c2. Blocks 64..67: zero hist; block 64 zeroes loss_part.
// Fragment layout: cbf[((chunk*4 + fid)*64 + lane)*8 + j], fid = split*2 + st,
// lane = kq*16 + col, code = chunk*16+col, dims d = st*32 + kq*8 + j.
__global__ __launch_bounds__(256) void prep_kernel(
    const float* __restrict__ cb, ushort* __restrict__ cbf,
    float* __restrict__ c2h, int* __restrict__ hist, float* __restrict__ loss_part) {
    __shared__ float s_c2[2][16];
    int tid  = threadIdx.x;
    int lane = tid & 63, wave = tid >> 6;
    int quad = lane >> 4, col = lane & 15;
    int bx   = blockIdx.x;

    if (bx >= 64) {
        hist[(bx - 64) * 256 + tid] = 0;
        if (bx == 64 && tid < 64) loss_part[tid] = 0.f;
        return;
    }
    int c = bx, fid = wave;
    int st = fid & 1, split = fid >> 1;
    int code  = c * 16 + col;
    int dbase = st * 32 + quad * 8;
    const float* cp = cb + code * 64 + dbase;
    float4v v0 = *(const float4v*)cp;
    float4v v1 = *(const float4v*)(cp + 4);
    float xs[8] = {v0.x, v0.y, v0.z, v0.w, v1.x, v1.y, v1.z, v1.w};
    short8 frag;
    float ssq = 0.f;
#pragma unroll
    for (int j = 0; j < 8; j++) {
        float x = xs[j];
        ssq = fmaf(x, x, ssq);
        unsigned hb = bf16_rne(x);
        if (split == 0) frag[j] = (short)hb;
        else            frag[j] = (short)bf16_rne(x - __uint_as_float(hb << 16));
    }
    *(short8*)(cbf + ((c * 4 + fid) * 64 + lane) * 8) = frag;   // contiguous 16B store
    if (split == 0) {                    // c2 from exact f32, deterministic order
        ssq += __shfl_xor(ssq, 16);      // sum over kq (lane bits 4..5)
        ssq += __shfl_xor(ssq, 32);
        if (quad == 0) s_c2[st][col] = ssq;
    }
    __syncthreads();
    if (tid < 16) c2h[c * 16 + tid] = -0.5f * (s_c2[0][tid] + s_c2[1][tid]);
}

// grid = 1024 blocks x 256 (4 waves = 4 blocks/CU = 16 waves/CU). Block = 64 tokens.
// wave: tokhalf = wave&1 (32 tokens), khalf = wave>>1 (chunks khalf*32 .. +31).
__global__ __launch_bounds__(256, 4) void vq_kernel(
    const float* __restrict__ z, const float* __restrict__ cb,
    const ushort* __restrict__ cbf, const float* __restrict__ c2h,
    float* __restrict__ out, float* __restrict__ loss_part, int* __restrict__ hist)
{
    __shared__ float s_q[64 * 65];       // gathered code rows, +1 pad (16.6 KB)
    __shared__ float s_ms[2][64];        // K-half merge: score
    __shared__ int   s_mi[2][64];        // K-half merge: index
    __shared__ int   s_idx[64];
    __shared__ float s_red[4];

    int tid  = threadIdx.x;
    int lane = tid & 63, wave = tid >> 6;
    int quad = lane >> 4, col = lane & 15;
    int bx   = blockIdx.x;

    int tokbase = bx * 64;
    int bb = tokbase >> 10, hwb = tokbase & 1023;
    const float* zb = z + bb * 65536 + hwb;
    int tokhalf = wave & 1, khalf = wave >> 1;

    // A-fragments: 2 groups x {hi,lo} x 2 K-steps, loaded once
    short8 ah[2][2], al[2][2];
#pragma unroll
    for (int g = 0; g < 2; g++) {
        int rel = tokhalf * 32 + g * 16 + col;       // token row m = lane&15
#pragma unroll
        for (int st = 0; st < 2; st++) {
            short8 h8, l8;
#pragma unroll
            for (int j = 0; j < 8; j++) {
                int d = st * 32 + quad * 8 + j;      // k = quad*8+j
                float x = zb[d * 1024 + rel];
                unsigned hb = bf16_rne(x);
                h8[j] = (short)hb;
                l8[j] = (short)bf16_rne(x - __uint_as_float(hb << 16));
            }
            ah[g][st] = h8; al[g][st] = l8;
        }
    }

    float best[2][4]; int bidx[2][4];
#pragma unroll
    for (int g = 0; g < 2; g++)
#pragma unroll
        for (int r = 0; r < 4; r++) { best[g][r] = -1e38f; bidx[g][r] = 0; }

    // k-loop: 32 chunks, register double-buffered B-frag prefetch, no barriers.
    // s_setprio(1) around the MFMA cluster: waves here are barrier-free independent
    // streams (the m191 regime where setprio pays), so prefer the MFMA-issuing wave.
    int cbase = khalf * 32;
    const ushort* cw = cbf + lane * 8;
    {
        const ushort* p0 = cw + cbase * 2048;
        short8 nb0 = *(const short8*)(p0 + 0);
        short8 nb1 = *(const short8*)(p0 + 512);
        short8 nb2 = *(const short8*)(p0 + 1024);
        short8 nb3 = *(const short8*)(p0 + 1536);
        float  nini = c2h[cbase * 16 + col];
        for (int cc = 0; cc < 32; cc++) {
            short8 bh0 = nb0, bh1 = nb1, bl0 = nb2, bl1 = nb3;
            float  ini = nini;
            if (cc < 31) {                            // prefetch next chunk
                const ushort* np = cw + (cbase + cc + 1) * 2048;
                nb0 = *(const short8*)(np + 0);
                nb1 = *(const short8*)(np + 512);
                nb2 = *(const short8*)(np + 1024);
                nb3 = *(const short8*)(np + 1536);
                nini = c2h[(cbase + cc + 1) * 16 + col];
            }
            int code = (cbase + cc) * 16 + col;
            __builtin_amdgcn_s_setprio(1);
#pragma unroll
            for (int g = 0; g < 2; g++) {
                float4v a0 = {ini, ini, ini, ini};    // score = dot - c2/2 (argmax)
                float4v a1 = {0.f, 0.f, 0.f, 0.f};
                a0 = __builtin_amdgcn_mfma_f32_16x16x32_bf16(ah[g][0], bh0, a0, 0, 0, 0);
                a1 = __builtin_amdgcn_mfma_f32_16x16x32_bf16(ah[g][1], bh1, a1, 0, 0, 0);
                a0 = __builtin_amdgcn_mfma_f32_16x16x32_bf16(ah[g][0], bl0, a0, 0, 0, 0);
                a1 = __builtin_amdgcn_mfma_f32_16x16x32_bf16(ah[g][1], bl1, a1, 0, 0, 0);
                a0 = __builtin_amdgcn_mfma_f32_16x16x32_bf16(al[g][0], bh0, a0, 0, 0, 0);
                a1 = __builtin_amdgcn_mfma_f32_16x16x32_bf16(al[g][1], bh1, a1, 0, 0, 0);
                a0 = __builtin_amdgcn_mfma_f32_16x16x32_bf16(al[g][0], bl0, a0, 0, 0, 0);
                a1 = __builtin_amdgcn_mfma_f32_16x16x32_bf16(al[g][1], bl1, a1, 0, 0, 0);
#pragma unroll
                for (int r = 0; r < 4; r++) {
                    float s = a0[r] + a1[r];
                    if (s > best[g][r]) { best[g][r] = s; bidx[g][r] = code; }  // strict >: first-min
                }
            }
            __builtin_amdgcn_s_setprio(0);
        }
    }

    // quad-reduction (C row = quad*4+r, col = code lane)
#pragma unroll
    for (int g = 0; g < 2; g++) {
#pragma unroll
        for (int r = 0; r < 4; r++) {
            float s = best[g][r]; int ix = bidx[g][r];
#pragma unroll
            for (int m = 1; m <= 8; m <<= 1) {
                float so = __shfl_xor(s, m);
                int   io = __shfl_xor(ix, m);
                if (so > s || (so == s && io < ix)) { s = so; ix = io; }
            }
            if (col == 0) {
                int t = tokhalf * 32 + g * 16 + quad * 4 + r;
                s_ms[khalf][t] = s; s_mi[khalf][t] = ix;
            }
        }
    }
    __syncthreads();

    // merge K-halves (half0 codes < half1 codes: tie -> half0 = first-min)
    if (tid < 64) {
        float s0 = s_ms[0][tid], s1 = s_ms[1][tid];
        int   i0 = s_mi[0][tid], i1 = s_mi[1][tid];
        int   ix = (s1 > s0) ? i1 : i0;
        s_idx[tid] = ix;
        atomicAdd(&hist[ix], 1);                       // one per token
    }
    __syncthreads();

    // gather selected code rows (wave-uniform row, 256B coalesced)
#pragma unroll
    for (int p = 0; p < 16; p++) {
        int i = p * 256 + tid;
        int t = i >> 6, d = i & 63;
        s_q[t * 65 + d] = cb[s_idx[t] * 64 + d];
    }
    __syncthreads();

    // straight-through output + loss (256B contiguous runs per wave)
    float ls = 0.f;
#pragma unroll 4
    for (int p = 0; p < 16; p++) {
        int i = p * 256 + tid;
        int d = i >> 6, t = i & 63;
        int a = d * 1024 + t;
        float zv = zb[a];
        float q  = s_q[t * 65 + d];                    // bank(t*65+d)=t+d: conflict-free
        float df = q - zv;
        out[bb * 65536 + hwb + a] = zv + df;           // z + (z_q - z)
        ls = fmaf(df, df, ls);
    }
#pragma unroll
    for (int off = 32; off; off >>= 1) ls += __shfl_down(ls, off);
    if (lane == 0) s_red[wave] = ls;
    __syncthreads();
    if (tid == 0) {
        float v = (s_red[0] + s_red[1]) + (s_red[2] + s_red[3]);
        atomicAdd(&loss_part[bx & 63], v);
    }
}

__global__ __launch_bounds__(1024) void finalize_kernel(
    const int* __restrict__ hist, const float* __restrict__ loss_part,
    const int* __restrict__ flg, float* __restrict__ out) {
    __shared__ float red[16];
    int   k = threadIdx.x;
    float e = (float)hist[k] * (1.0f / 65536.0f);
    float v = e * logf(e + 1e-10f);
#pragma unroll
    for (int off = 32; off; off >>= 1) v += __shfl_down(v, off);
    if ((k & 63) == 0) red[k >> 6] = v;
    __syncthreads();
    if (k == 0) {
        float s = 0.f;
#pragma unroll
        for (int i = 0; i < 16; i++) s += red[i];
        out[NELEM + 1] = expf(-s);                     // perplexity

        float ls = 0.f;
        for (int i = 0; i < 64; i++) ls += loss_part[i];
        float m    = ls * (1.0f / (float)NELEM);
        out[NELEM] = (*flg) ? (0.25f * m + m) : 0.0f;  // BETA*mean + mean
    }
}

extern "C" void kernel_launch(void* const* d_in, const int* in_sizes, int n_in,
                              void* d_out, int out_size, void* d_ws, size_t ws_size,
                              hipStream_t stream) {
    const float* z   = (const float*)d_in[0];   // (64,64,32,32) f32 NCHW
    const float* cb  = (const float*)d_in[1];   // (1024,64) f32
    const int*   flg = (const int*)d_in[3];     // flg_train

    float* out = (float*)d_out;
    char*  ws  = (char*)d_ws;

    ushort* cbf       = (ushort*)(ws + WS_CBF);
    float*  c2h       = (float*)(ws + WS_C2H);
    int*    hist      = (int*)(ws + WS_HIST);
    float*  loss_part = (float*)(ws + WS_LOSS);

    prep_kernel<<<68, 256, 0, stream>>>(cb, cbf, c2h, hist, loss_part);
    vq_kernel<<<1024, 256, 0, stream>>>(z, cb, cbf, c2h, out, loss_part, hist);
    finalize_kernel<<<1, 1024, 0, stream>>>(hist, loss_part, flg, out);
}